// Round 3
// baseline (499.394 us; speedup 1.0000x reference)
//
#include <hip/hip_runtime.h>
#include <math.h>

#define NPCH 49
#define NA 18
#define NB 8192
#define TOTAL (NB*NPCH)    // 401408

typedef __attribute__((ext_vector_type(8))) short bf16x8;
typedef __attribute__((ext_vector_type(4))) float f32x4;

__device__ __forceinline__ unsigned short f2bf(float f) {
    unsigned int u = __float_as_uint(f);
    return (unsigned short)((u + 0x7FFFu + ((u >> 16) & 1u)) >> 16);
}

// bf16 weight buffer layout (ushort units), built by prep_weights
#define W1_OFF  0          // We1t [256][288]
#define W2_OFF  73728      // We2t [128][256]
#define W3_OFF  106496     // We3t [32][128]  (rows 18..31 zero)
#define WA1_OFF 110592     // Wa1t [64][160]  (k 144..159 zero)
#define WA2_OFF 120832     // Wa2t [64][64]
#define W_TOTAL 124928

__global__ __launch_bounds__(256)
void prep_weights(const float* __restrict__ We1, const float* __restrict__ We2,
                  const float* __restrict__ We3, const float* __restrict__ Wa1,
                  const float* __restrict__ Wa2, unsigned short* __restrict__ wb)
{
    int i = blockIdx.x * 256 + threadIdx.x;
    if (i >= W_TOTAL) return;
    int idx = i;
    float v;
    if (idx < 73728) {                       // We1t[n][k] = We1[k][n], 288x256
        int n = idx / 288, k = idx - n * 288;
        v = We1[k * 256 + n];
    } else if ((idx -= 73728) < 32768) {     // We2t, 256x128
        int n = idx / 256, k = idx - n * 256;
        v = We2[k * 128 + n];
    } else if ((idx -= 32768) < 4096) {      // We3t, 128x18 padded to 32 cols
        int n = idx / 128, k = idx - n * 128;
        v = (n < 18) ? We3[k * 18 + n] : 0.0f;
    } else if ((idx -= 4096) < 10240) {      // Wa1t, 144x64 padded to K=160
        int n = idx / 160, k = idx - n * 160;
        v = (k < 144) ? Wa1[k * 64 + n] : 0.0f;
    } else {                                 // Wa2t, 64x64
        idx -= 10240;
        int n = idx / 64, k = idx - n * 64;
        v = Wa2[k * 64 + n];
    }
    wb[i] = f2bf(v);
}

// ---------------------------------------------------------------------------
// Fused MFMA kernel: 1 block = 1 image (49 patches, M-tile 64 w/ 15 dead rows).
// Phase 0: coalesced float4 image load -> LDS bf16 IMG[diff|now] (28224 B).
// Phase 1: build Ein A-fragments from IMG via ds_read_u16 (no global scatter).
// Phases 2+: identical MFMA pipeline to validated R2 kernel, writes guarded.
// LDS overlay (69184 B, 2 blocks/CU):
//   Ein [0,40960) | IMG [40960,69184)
//   HA1 [49152,57344) + APT [57344,58368) overlay IMG (dead after Ein build)
//   H1 [0,32768) overlays Ein (after e1 barrier); H2 [32768,49152) (dead zones)
// ---------------------------------------------------------------------------
__global__ __launch_bounds__(256)
void fused_mfma_kernel(const float* __restrict__ last_s, const float* __restrict__ now_s,
                       const unsigned short* __restrict__ wb,
                       const float* __restrict__ be1, const float* __restrict__ be2,
                       const float* __restrict__ be3, const float* __restrict__ ba1,
                       const float* __restrict__ ba2, const float* __restrict__ ba3,
                       const float* __restrict__ Wa3,
                       float* __restrict__ out_each, float* __restrict__ ws_alpha)
{
    __shared__ __align__(16) unsigned char smem[69184];
    unsigned short* Ein = (unsigned short*)smem;            // [4][10][512]
    unsigned short* IMG = (unsigned short*)(smem + 40960);  // [2][7056] diff|now
    unsigned short* H1  = (unsigned short*)smem;            // [4][8][512] overlay
    unsigned short* H2  = (unsigned short*)(smem + 32768);  // [4][4][512]
    unsigned short* HA1 = (unsigned short*)(smem + 49152);  // [4][2][512]
    float*          APT = (float*)(smem + 57344);           // [4][64]

    const int t    = threadIdx.x;
    const int lane = t & 63;
    const int wid  = t >> 6;
    const int g    = lane >> 4;
    const int rl   = lane & 15;
    const int img  = blockIdx.x;

    // ---------------- phase 0: coalesced image load -> IMG bf16 ----------------
    {
        const float* nowI  = now_s  + (size_t)img * 7056;
        const float* lastI = last_s + (size_t)img * 7056;
        for (int i = t; i < 1764; i += 256) {
            const float4 n4 = *(const float4*)(nowI + i * 4);
            const float4 l4 = *(const float4*)(lastI + i * 4);
            ushort4 d4, w4;
            d4.x = f2bf((n4.x - l4.x) * (1.0f / 255.0f));
            d4.y = f2bf((n4.y - l4.y) * (1.0f / 255.0f));
            d4.z = f2bf((n4.z - l4.z) * (1.0f / 255.0f));
            d4.w = f2bf((n4.w - l4.w) * (1.0f / 255.0f));
            w4.x = f2bf(n4.x * (1.0f / 255.0f));
            w4.y = f2bf(n4.y * (1.0f / 255.0f));
            w4.z = f2bf(n4.z * (1.0f / 255.0f));
            w4.w = f2bf(n4.w * (1.0f / 255.0f));
            *(ushort4*)(IMG + i * 4)        = d4;
            *(ushort4*)(IMG + 7056 + i * 4) = w4;
        }
    }
    __syncthreads();

    // ---------------- phase 1: build Ein A-fragments from IMG ----------------
    {
        const int p = wid * 16 + rl;
        const bf16x8 z = {0, 0, 0, 0, 0, 0, 0, 0};
        *(bf16x8*)(Ein + (wid * 10 + 9) * 512 + lane * 8) = z;   // zero pad slot
        if (p < NPCH) {
            const int pi = p / 7, pj = p - pi * 7;
            const int pbase = pi * 1008 + pj * 12;   // pi*12*84 + pj*12
            #pragma unroll
            for (int s = 0; s < 9; ++s) {
                union { unsigned short u[8]; bf16x8 v; } pk;
                #pragma unroll
                for (int j = 0; j < 8; ++j) {
                    const int k   = s * 32 + g * 8 + j;
                    const int sel = (k >= 144) ? 1 : 0;
                    const int f   = k - sel * 144;
                    const int fr  = f / 12, fc = f - fr * 12;
                    pk.u[j] = IMG[sel * 7056 + pbase + fr * 84 + fc];
                }
                *(bf16x8*)(Ein + (wid * 10 + s) * 512 + lane * 8) = pk.v;
            }
        } else {
            #pragma unroll
            for (int s = 0; s < 9; ++s)
                *(bf16x8*)(Ein + (wid * 10 + s) * 512 + lane * 8) = z;
        }
    }
    __syncthreads();   // Ein ready; IMG dead -> HA1/APT may overlay

    // ---------------- alpha layer 1: 144(->160) -> 64 ----------------
    {
        const int col = wid * 16 + rl;
        const float b1 = ba1[col];
        f32x4 acc[4];
        #pragma unroll
        for (int mt = 0; mt < 4; ++mt) acc[mt] = (f32x4){b1, b1, b1, b1};
        for (int sa = 0; sa < 5; ++sa) {
            const int ok = 144 + sa * 32 + g * 8;   // offset into Ein's "now" half
            bf16x8 bfr = *(const bf16x8*)(wb + WA1_OFF + col * 160 + sa * 32 + g * 8);
            #pragma unroll
            for (int mt = 0; mt < 4; ++mt) {
                bf16x8 af = *(const bf16x8*)(Ein + (mt * 10 + (ok >> 5)) * 512 +
                                             ((ok >> 3) & 3) * 128 + rl * 8);
                acc[mt] = __builtin_amdgcn_mfma_f32_16x16x32_bf16(af, bfr, acc[mt], 0, 0, 0);
            }
        }
        const int sA  = wid >> 1;
        const int hiA = (wid & 1) * 2 + (rl >> 3);
        const int jA  = rl & 7;
        #pragma unroll
        for (int mt = 0; mt < 4; ++mt) {
            unsigned short* base = HA1 + (mt * 2 + sA) * 512 + hiA * 128 + (g * 4) * 8 + jA;
            #pragma unroll
            for (int r = 0; r < 4; ++r)
                base[r * 8] = f2bf(fmaxf(acc[mt][r], 0.0f));
        }
    }
    __syncthreads();

    // ---------------- alpha layer 2 + fused layer 3 ----------------
    {
        const int col = wid * 16 + rl;
        const float b2 = ba2[col];
        const float w3 = Wa3[col];
        f32x4 acc[4];
        #pragma unroll
        for (int mt = 0; mt < 4; ++mt) acc[mt] = (f32x4){b2, b2, b2, b2};
        for (int s = 0; s < 2; ++s) {
            bf16x8 bfr = *(const bf16x8*)(wb + WA2_OFF + col * 64 + s * 32 + g * 8);
            #pragma unroll
            for (int mt = 0; mt < 4; ++mt) {
                bf16x8 af = *(const bf16x8*)(HA1 + (mt * 2 + s) * 512 + lane * 8);
                acc[mt] = __builtin_amdgcn_mfma_f32_16x16x32_bf16(af, bfr, acc[mt], 0, 0, 0);
            }
        }
        #pragma unroll
        for (int mt = 0; mt < 4; ++mt) {
            #pragma unroll
            for (int r = 0; r < 4; ++r) {
                float v = fmaxf(acc[mt][r], 0.0f) * w3;
                v += __shfl_xor(v, 1); v += __shfl_xor(v, 2);
                v += __shfl_xor(v, 4); v += __shfl_xor(v, 8);
                if (rl == 0) APT[wid * 64 + mt * 16 + g * 4 + r] = v;
            }
        }
    }
    __syncthreads();

    // alpha logits finalize (guarded: only 49 valid patches)
    if (t < NPCH)
        ws_alpha[img * NPCH + t] = APT[t] + APT[64 + t] + APT[128 + t] + APT[192 + t] + ba3[0];

    // ---------------- e layer 1: 288 -> 256 ----------------
    f32x4 acc1[4][4];
    {
        #pragma unroll
        for (int nt = 0; nt < 4; ++nt) {
            const float b = be1[wid * 64 + nt * 16 + rl];
            #pragma unroll
            for (int mt = 0; mt < 4; ++mt) acc1[mt][nt] = (f32x4){b, b, b, b};
        }
        for (int s = 0; s < 9; ++s) {
            bf16x8 a0f = *(const bf16x8*)(Ein + (0 * 10 + s) * 512 + lane * 8);
            bf16x8 a1f = *(const bf16x8*)(Ein + (1 * 10 + s) * 512 + lane * 8);
            bf16x8 a2f = *(const bf16x8*)(Ein + (2 * 10 + s) * 512 + lane * 8);
            bf16x8 a3f = *(const bf16x8*)(Ein + (3 * 10 + s) * 512 + lane * 8);
            #pragma unroll
            for (int nt = 0; nt < 4; ++nt) {
                bf16x8 bfr = *(const bf16x8*)(wb + W1_OFF +
                                (wid * 64 + nt * 16 + rl) * 288 + s * 32 + g * 8);
                acc1[0][nt] = __builtin_amdgcn_mfma_f32_16x16x32_bf16(a0f, bfr, acc1[0][nt], 0, 0, 0);
                acc1[1][nt] = __builtin_amdgcn_mfma_f32_16x16x32_bf16(a1f, bfr, acc1[1][nt], 0, 0, 0);
                acc1[2][nt] = __builtin_amdgcn_mfma_f32_16x16x32_bf16(a2f, bfr, acc1[2][nt], 0, 0, 0);
                acc1[3][nt] = __builtin_amdgcn_mfma_f32_16x16x32_bf16(a3f, bfr, acc1[3][nt], 0, 0, 0);
            }
        }
    }
    __syncthreads();    // all Ein reads complete before H1 overlay

    // H1 fragment writes (relu)
    {
        #pragma unroll
        for (int mt = 0; mt < 4; ++mt) {
            #pragma unroll
            for (int nt = 0; nt < 4; ++nt) {
                const int col = wid * 64 + nt * 16 + rl;
                unsigned short* base = H1 + (mt * 8 + (col >> 5)) * 512 +
                                       ((col >> 3) & 3) * 128 + (g * 4) * 8 + (col & 7);
                #pragma unroll
                for (int r = 0; r < 4; ++r)
                    base[r * 8] = f2bf(fmaxf(acc1[mt][nt][r], 0.0f));
            }
        }
    }
    __syncthreads();

    // ---------------- e layer 2: 256 -> 128 ----------------
    {
        f32x4 acc2[4][2];
        #pragma unroll
        for (int nt = 0; nt < 2; ++nt) {
            const float b = be2[wid * 32 + nt * 16 + rl];
            #pragma unroll
            for (int mt = 0; mt < 4; ++mt) acc2[mt][nt] = (f32x4){b, b, b, b};
        }
        for (int s = 0; s < 8; ++s) {
            bf16x8 a0f = *(const bf16x8*)(H1 + (0 * 8 + s) * 512 + lane * 8);
            bf16x8 a1f = *(const bf16x8*)(H1 + (1 * 8 + s) * 512 + lane * 8);
            bf16x8 a2f = *(const bf16x8*)(H1 + (2 * 8 + s) * 512 + lane * 8);
            bf16x8 a3f = *(const bf16x8*)(H1 + (3 * 8 + s) * 512 + lane * 8);
            #pragma unroll
            for (int nt = 0; nt < 2; ++nt) {
                bf16x8 bfr = *(const bf16x8*)(wb + W2_OFF +
                                (wid * 32 + nt * 16 + rl) * 256 + s * 32 + g * 8);
                acc2[0][nt] = __builtin_amdgcn_mfma_f32_16x16x32_bf16(a0f, bfr, acc2[0][nt], 0, 0, 0);
                acc2[1][nt] = __builtin_amdgcn_mfma_f32_16x16x32_bf16(a1f, bfr, acc2[1][nt], 0, 0, 0);
                acc2[2][nt] = __builtin_amdgcn_mfma_f32_16x16x32_bf16(a2f, bfr, acc2[2][nt], 0, 0, 0);
                acc2[3][nt] = __builtin_amdgcn_mfma_f32_16x16x32_bf16(a3f, bfr, acc2[3][nt], 0, 0, 0);
            }
        }
        // H2 fragment writes (relu); H2 region disjoint from H1
        #pragma unroll
        for (int mt = 0; mt < 4; ++mt) {
            #pragma unroll
            for (int nt = 0; nt < 2; ++nt) {
                const int c2 = nt * 16 + rl;   // col = wid*32 + c2, s2 = wid
                unsigned short* base = H2 + (mt * 4 + wid) * 512 +
                                       ((c2 >> 3) & 3) * 128 + (g * 4) * 8 + (c2 & 7);
                #pragma unroll
                for (int r = 0; r < 4; ++r)
                    base[r * 8] = f2bf(fmaxf(acc2[mt][nt][r], 0.0f));
            }
        }
    }
    __syncthreads();

    // ---------------- e layer 3: 128 -> 18 (padded 32) + log_softmax ----------------
    {
        f32x4 acc3[2];
        #pragma unroll
        for (int nt = 0; nt < 2; ++nt) {
            const int col = nt * 16 + rl;
            const float b = (col < NA) ? be3[col] : 0.0f;
            acc3[nt] = (f32x4){b, b, b, b};
        }
        for (int s = 0; s < 4; ++s) {
            bf16x8 af = *(const bf16x8*)(H2 + (wid * 4 + s) * 512 + lane * 8);
            #pragma unroll
            for (int nt = 0; nt < 2; ++nt) {
                bf16x8 bfr = *(const bf16x8*)(wb + W3_OFF + (nt * 16 + rl) * 128 + s * 32 + g * 8);
                acc3[nt] = __builtin_amdgcn_mfma_f32_16x16x32_bf16(af, bfr, acc3[nt], 0, 0, 0);
            }
        }
        const bool v1 = (rl < 2);
        #pragma unroll
        for (int r = 0; r < 4; ++r) {
            const int p3 = wid * 16 + g * 4 + r;   // patch row of this C element
            float x0 = acc3[0][r];
            float x1 = acc3[1][r];
            float m = fmaxf(x0, v1 ? x1 : -3.0e38f);
            m = fmaxf(m, __shfl_xor(m, 1)); m = fmaxf(m, __shfl_xor(m, 2));
            m = fmaxf(m, __shfl_xor(m, 4)); m = fmaxf(m, __shfl_xor(m, 8));
            float sm = expf(x0 - m) + (v1 ? expf(x1 - m) : 0.0f);
            sm += __shfl_xor(sm, 1); sm += __shfl_xor(sm, 2);
            sm += __shfl_xor(sm, 4); sm += __shfl_xor(sm, 8);
            const float L = m + logf(sm);
            if (p3 < NPCH) {
                float* o = out_each + (size_t)(img * NPCH + p3) * NA;
                o[rl] = x0 - L;
                if (v1) o[16 + rl] = x1 - L;
            }
        }
    }
}

// ---------------------------------------------------------------------------
// Kernel B: one wave per batch element (unchanged, validated).
// ---------------------------------------------------------------------------
__global__ __launch_bounds__(64)
void alpha_combine_kernel(const float* __restrict__ ws_alpha,
                          const float* __restrict__ out_each,
                          float* __restrict__ out_probs,
                          float* __restrict__ ws_ent)
{
    const int b = blockIdx.x;
    const int lane = threadIdx.x;

    float lg = (lane < NPCH) ? ws_alpha[b * NPCH + lane] : -3.0e38f;
    float m = lg;
    #pragma unroll
    for (int off = 32; off > 0; off >>= 1) m = fmaxf(m, __shfl_xor(m, off, 64));
    float ex = (lane < NPCH) ? expf(lg - m) : 0.0f;
    float s = ex;
    #pragma unroll
    for (int off = 32; off > 0; off >>= 1) s += __shfl_xor(s, off, 64);
    const float ls = logf(s);
    const float alpha = ex / s;

    float ent = (lane < NPCH) ? alpha * (lg - m - ls) : 0.0f;
    #pragma unroll
    for (int off = 32; off > 0; off >>= 1) ent += __shfl_xor(ent, off, 64);
    if (lane == 0) ws_ent[b] = ent;

    float acc = 0.0f;
    const float* eb = out_each + (size_t)b * NPCH * NA;
    for (int p = 0; p < NPCH; ++p) {
        const float ap = __shfl(alpha, p, 64);
        if (lane < NA) acc += ap * eb[p * NA + lane];
    }
    float mm = (lane < NA) ? acc : -3.0e38f;
    #pragma unroll
    for (int off = 32; off > 0; off >>= 1) mm = fmaxf(mm, __shfl_xor(mm, off, 64));
    float ee = (lane < NA) ? expf(acc - mm) : 0.0f;
    #pragma unroll
    for (int off = 32; off > 0; off >>= 1) ee += __shfl_xor(ee, off, 64);
    if (lane < NA) out_probs[b * NA + lane] = acc - mm - logf(ee);
}

__global__ __launch_bounds__(256)
void ent_reduce_kernel(const float* __restrict__ ws_ent, float* __restrict__ out_scalar)
{
    float s = 0.0f;
    for (int i = threadIdx.x; i < NB; i += 256) s += ws_ent[i];
    #pragma unroll
    for (int off = 32; off > 0; off >>= 1) s += __shfl_xor(s, off, 64);
    __shared__ float ps[4];
    if ((threadIdx.x & 63) == 0) ps[threadIdx.x >> 6] = s;
    __syncthreads();
    if (threadIdx.x == 0)
        out_scalar[0] = (ps[0] + ps[1] + ps[2] + ps[3]) * (1.0f / NB);
}

extern "C" void kernel_launch(void* const* d_in, const int* in_sizes, int n_in,
                              void* d_out, int out_size, void* d_ws, size_t ws_size,
                              hipStream_t stream)
{
    (void)in_sizes; (void)n_in; (void)out_size; (void)ws_size;

    const float* last_s = (const float*)d_in[0];
    const float* now_s  = (const float*)d_in[1];
    const float* We1 = (const float*)d_in[2];  const float* be1 = (const float*)d_in[3];
    const float* We2 = (const float*)d_in[4];  const float* be2 = (const float*)d_in[5];
    const float* We3 = (const float*)d_in[6];  const float* be3 = (const float*)d_in[7];
    const float* Wa1 = (const float*)d_in[8];  const float* ba1 = (const float*)d_in[9];
    const float* Wa2 = (const float*)d_in[10]; const float* ba2 = (const float*)d_in[11];
    const float* Wa3 = (const float*)d_in[12]; const float* ba3 = (const float*)d_in[13];

    float* out = (float*)d_out;
    float* out_probs = out;                    // [B,18]
    float* out_ent   = out + NB * NA;          // scalar
    float* out_each  = out + NB * NA + 1;      // [B,49,18]

    float* ws_alpha = (float*)d_ws;            // [TOTAL]
    float* ws_ent   = ws_alpha + TOTAL;        // [NB]
    unsigned short* wbuf = (unsigned short*)(ws_ent + NB);  // bf16 weights

    prep_weights<<<dim3((W_TOTAL + 255) / 256), dim3(256), 0, stream>>>(
        We1, We2, We3, Wa1, Wa2, wbuf);

    fused_mfma_kernel<<<dim3(NB), dim3(256), 0, stream>>>(
        last_s, now_s, wbuf, be1, be2, be3, ba1, ba2, ba3, Wa3,
        out_each, ws_alpha);

    alpha_combine_kernel<<<dim3(NB), dim3(64), 0, stream>>>(
        ws_alpha, out_each, out_probs, ws_ent);

    ent_reduce_kernel<<<dim3(1), dim3(256), 0, stream>>>(ws_ent, out_ent);
}